// Round 9
// baseline (596.632 us; speedup 1.0000x reference)
//
#include <hip/hip_runtime.h>
#include <hip/hip_bf16.h>

#define NN 50000
#define NE 800000
#define TE 850000
#define EPSN 1e-12f

// Validated: inputs f32, output f32 (R2/R4); partitionable threefry (R2/R4); exp w/o max OK;
// bf16 intermediates FAIL (R5); hier scan (R6); 64-row gemm tiles for balance (R7);
// R8 NaN = RINV read/write aliasing race in fused attn2+gemm3 -> separate RINV3 buffer here.

// ---- workspace layout (bytes, 16B aligned) ----
#define H_OFF    0ull          // f32 [50000][200] : H1 then H2
#define A_OFF    40000000ull   // f32 [50000][200] : A1
#define H3_OFF   80000000ull   // f32 [50000][2]
#define RINV_OFF 80400000ull   // f32 [50000]   (layer-1 then layer-2 norms)
#define OFFS_OFF 80600000ull   // int [50001]
#define DEG_OFF  80800016ull   // int [50000]
#define CURS_OFF 81000016ull   // int [50000]
#define ESRC_OFF 81200016ull   // int [850000]
#define CHNK_OFF 84600016ull   // int [64]
#define RINV3_OFF 84600272ull  // f32 [50000]   (layer-3 norms — MUST be distinct from RINV, R8 race)

// ---------------- threefry2x32, 20 rounds ----------------
__host__ __device__ inline void tf20(unsigned k0, unsigned k1, unsigned& x0, unsigned& x1) {
  unsigned ks2 = k0 ^ k1 ^ 0x1BD11BDAu;
  x0 += k0; x1 += k1;
#define TFR(r) { x0 += x1; x1 = ((x1 << (r)) | (x1 >> (32 - (r)))) ^ x0; }
  TFR(13) TFR(15) TFR(26) TFR(6)
  x0 += k1;  x1 += ks2 + 1u;
  TFR(17) TFR(29) TFR(16) TFR(24)
  x0 += ks2; x1 += k0 + 2u;
  TFR(13) TFR(15) TFR(26) TFR(6)
  x0 += k0;  x1 += k1 + 3u;
  TFR(17) TFR(29) TFR(16) TFR(24)
  x0 += k1;  x1 += ks2 + 4u;
  TFR(13) TFR(15) TFR(26) TFR(6)
  x0 += ks2; x1 += k0 + 5u;
#undef TFR
}

__device__ __forceinline__ float dropf(float val, unsigned k0, unsigned k1, unsigned i) {
  unsigned x0 = 0u, x1 = i;
  tf20(k0, k1, x0, x1);
  unsigned bits = x0 ^ x1;
  float u = __uint_as_float((bits >> 9) | 0x3F800000u) - 1.0f;
  return (u < 0.9f) ? val * (1.0f / 0.9f) : 0.0f;
}

__device__ __forceinline__ float wave_sum(float x) {
  x += __shfl_xor(x, 32); x += __shfl_xor(x, 16); x += __shfl_xor(x, 8);
  x += __shfl_xor(x, 4);  x += __shfl_xor(x, 2);  x += __shfl_xor(x, 1);
  return x;
}

// ---------------- CSR build (R7-validated) ----------------
__global__ __launch_bounds__(256) void csr_zero_kernel(int* __restrict__ p, int n) {
  int stride = gridDim.x * 256;
  for (int i = blockIdx.x * 256 + threadIdx.x; i < n; i += stride) p[i] = 0;
}

__global__ __launch_bounds__(256) void csr_hist_kernel(const int* __restrict__ ei, int* __restrict__ deg) {
  int e = blockIdx.x * 256 + threadIdx.x;
  if (e >= TE) return;
  int d = (e < NE) ? ei[NE + e] : (e - NE);
  atomicAdd(&deg[d], 1);
}

__global__ __launch_bounds__(256) void csr_scan1_kernel(const int* __restrict__ deg,
                                                        int* __restrict__ offs,
                                                        int* __restrict__ chunk) {
  __shared__ int lds[8];
  int t = threadIdx.x;
  int base = blockIdx.x * 1024 + t * 4;
  int d[4];
#pragma unroll
  for (int j = 0; j < 4; j++) d[j] = (base + j < NN) ? deg[base + j] : 0;
  int ts = d[0] + d[1] + d[2] + d[3];
  int lane = t & 63, wave = t >> 6;
  int inc = ts;
#pragma unroll
  for (int sh = 1; sh < 64; sh <<= 1) { int u = __shfl_up(inc, sh); if (lane >= sh) inc += u; }
  if (lane == 63) lds[wave] = inc;
  __syncthreads();
  if (t == 0) { int s = 0; for (int w = 0; w < 4; w++) { int x = lds[w]; lds[w] = s; s += x; } lds[4] = s; }
  __syncthreads();
  int p = lds[wave] + inc - ts;
#pragma unroll
  for (int j = 0; j < 4; j++) { if (base + j < NN) offs[base + j] = p; p += d[j]; }
  if (t == 255) chunk[blockIdx.x] = lds[4];
}

__global__ __launch_bounds__(64) void csr_scan2_kernel(int* __restrict__ chunk) {
  int t = threadIdx.x;
  int v = (t < 49) ? chunk[t] : 0;
  int inc = v;
#pragma unroll
  for (int sh = 1; sh < 64; sh <<= 1) { int u = __shfl_up(inc, sh); if (t >= sh) inc += u; }
  if (t < 49) chunk[t] = inc - v;
}

__global__ __launch_bounds__(256) void csr_scan3_kernel(int* __restrict__ offs,
                                                        const int* __restrict__ chunk,
                                                        int* __restrict__ curs) {
  int i = blockIdx.x * 256 + threadIdx.x;
  if (i < NN) {
    int val = offs[i] + chunk[i >> 10];
    offs[i] = val;
    curs[i] = val;
  }
  if (i == 0) offs[NN] = TE;
}

__global__ __launch_bounds__(256) void csr_scatter_kernel(const int* __restrict__ ei,
                                                          int* __restrict__ curs,
                                                          int* __restrict__ esrc) {
  int e = blockIdx.x * 256 + threadIdx.x;
  if (e >= TE) return;
  int s, d;
  if (e < NE) { s = ei[e]; d = ei[NE + e]; } else { s = d = e - NE; }
  int pos = atomicAdd(&curs[d], 1);
  esrc[pos] = s;
}

// ---------------- tiled f32 GEMM, 64-row tiles (782 blocks, balanced) ----------------
template<int K, int KT, int NLP, int N>
__device__ __forceinline__ void gemm_body(const float* __restrict__ A,
                                          const float* __restrict__ W,
                                          float* __restrict__ H,
                                          float* __restrict__ RINV, int M) {
  constexpr int CPT = NLP / 4, KTP = KT + 1, NV = N / 4, QV = CPT / 4;
  __shared__ float As[64 * KTP];
  __shared__ float Ws[KT * NLP];
  const float4* A4 = (const float4*)A;
  const float4* W4 = (const float4*)W;
  const float4* Ws4 = (const float4*)Ws;

  int t = threadIdx.x, rgrp = t >> 2, cg = t & 3;
  int row0 = blockIdx.x * 64;
  float acc[CPT];
#pragma unroll
  for (int j = 0; j < CPT; j++) acc[j] = 0.f;

  for (int k0 = 0; k0 < K; k0 += KT) {
    __syncthreads();
    for (int idx = t; idx < 64 * (KT / 4); idx += 256) {
      int r = idx / (KT / 4), cq = idx - r * (KT / 4);
      int gr = row0 + r;
      float4 v = (gr < M) ? A4[(size_t)gr * (K / 4) + (k0 / 4) + cq]
                          : make_float4(0.f, 0.f, 0.f, 0.f);
      float* dst = &As[r * KTP + cq * 4];
      dst[0] = v.x; dst[1] = v.y; dst[2] = v.z; dst[3] = v.w;
    }
    for (int idx = t; idx < KT * NV; idx += 256) {
      int kk = idx / NV, cq = idx - kk * NV;
      *(float4*)&Ws[kk * NLP + cq * 4] = W4[(size_t)(k0 + kk) * NV + cq];
    }
    if (NLP > N) {
      for (int idx = t; idx < KT * ((NLP - N) / 4); idx += 256) {
        int kk = idx / ((NLP - N) / 4), cq = idx - kk * ((NLP - N) / 4);
        *(float4*)&Ws[kk * NLP + N + cq * 4] = make_float4(0.f, 0.f, 0.f, 0.f);
      }
    }
    __syncthreads();
#pragma unroll
    for (int kk = 0; kk < KT; kk++) {
      float a0 = As[rgrp * KTP + kk];
#pragma unroll
      for (int q = 0; q < QV; q++) {
        float4 wv = Ws4[(kk * NLP + cg * CPT) / 4 + q];
        acc[q * 4 + 0] = fmaf(a0, wv.x, acc[q * 4 + 0]);
        acc[q * 4 + 1] = fmaf(a0, wv.y, acc[q * 4 + 1]);
        acc[q * 4 + 2] = fmaf(a0, wv.z, acc[q * 4 + 2]);
        acc[q * 4 + 3] = fmaf(a0, wv.w, acc[q * 4 + 3]);
      }
    }
  }

  int gr = row0 + rgrp;
  float ss = 0.f;
#pragma unroll
  for (int j = 0; j < CPT; j++) {
    float v = acc[j];
    ss += v * v;
    int c = cg * CPT + j;
    if (gr < M && c < N) H[(size_t)gr * N + c] = v;
  }
  ss += __shfl_xor(ss, 1); ss += __shfl_xor(ss, 2);
  if (cg == 0 && gr < M) RINV[gr] = 1.0f / fmaxf(sqrtf(ss), EPSN);
}

__global__ __launch_bounds__(256) void gemm1_kernel(const float* A, const float* W,
                                                    float* H, float* RINV, int M) {
  gemm_body<128, 32, 208, 200>(A, W, H, RINV, M);
}
__global__ __launch_bounds__(256) void gemm2_kernel(const float* A, const float* W,
                                                    float* H, float* RINV, int M) {
  gemm_body<200, 40, 112, 100>(A, W, H, RINV, M);
}

// ---------------- fused attention: wave/dst, vectorized gathers, 4-edge unroll ----------------
// G3FUSE: fold layer-3 projection (W3 [100][2]) + row-norm into the epilogue; writes H3/RINV3.
template<int D, int VEC, bool DROP, bool G3FUSE>
__device__ __forceinline__ void attn_body(const float* __restrict__ H,
                                          const float* __restrict__ RINV,
                                          const int* __restrict__ OFFS,
                                          const int* __restrict__ ESRC,
                                          const float* __restrict__ BETA,
                                          float* __restrict__ OUT,
                                          const float* __restrict__ W3g,
                                          float* __restrict__ H3,
                                          float* __restrict__ RINVO,
                                          unsigned k0, unsigned k1) {
  constexpr int NL = D / VEC;                  // 50 active lanes
  int v = blockIdx.x * 4 + (threadIdx.x >> 6);
  int lane = threadIdx.x & 63;
  bool act = lane < NL;
  const float* hrow = H + (size_t)v * D + lane * VEC;
  float hd[VEC];
#pragma unroll
  for (int j = 0; j < VEC; j++) hd[j] = 0.f;
  if (act) {
    if (VEC == 4) { float4 tv = *(const float4*)hrow; hd[0] = tv.x; hd[1] = tv.y; hd[2] = tv.z; hd[3] = tv.w; }
    else          { float2 tv = *(const float2*)hrow; hd[0] = tv.x; hd[1] = tv.y; }
  }
  float bd = BETA[0] * RINV[v];
  int e0 = OFFS[v], e1 = OFFS[v + 1];

  float s = 0.0f;
  float acc[VEC];
#pragma unroll
  for (int j = 0; j < VEC; j++) acc[j] = 0.0f;

  int idx = e0;
  for (; idx + 4 <= e1; idx += 4) {
    int   u[4];
    float r[4], dt[4], hs[4][VEC];
#pragma unroll
    for (int m = 0; m < 4; m++) u[m] = ESRC[idx + m];
#pragma unroll
    for (int m = 0; m < 4; m++) r[m] = RINV[u[m]];
#pragma unroll
    for (int m = 0; m < 4; m++) {
      const float* p = H + (size_t)u[m] * D + lane * VEC;
#pragma unroll
      for (int j = 0; j < VEC; j++) hs[m][j] = 0.f;
      if (act) {
        if (VEC == 4) { float4 a = *(const float4*)p; hs[m][0] = a.x; hs[m][1] = a.y; hs[m][2] = a.z; hs[m][3] = a.w; }
        else          { float2 a = *(const float2*)p; hs[m][0] = a.x; hs[m][1] = a.y; }
      }
    }
#pragma unroll
    for (int m = 0; m < 4; m++) {
      float d = 0.f;
#pragma unroll
      for (int j = 0; j < VEC; j++) d = fmaf(hd[j], hs[m][j], d);
      dt[m] = wave_sum(d);
    }
#pragma unroll
    for (int m = 0; m < 4; m++) {
      float w = __expf(bd * dt[m] * r[m]);
      s += w;
#pragma unroll
      for (int j = 0; j < VEC; j++) acc[j] = fmaf(w, hs[m][j], acc[j]);
    }
  }
  for (; idx < e1; ++idx) {
    int u0 = ESRC[idx];
    float r0 = RINV[u0];
    const float* p0 = H + (size_t)u0 * D + lane * VEC;
    float h0[VEC];
#pragma unroll
    for (int j = 0; j < VEC; j++) h0[j] = 0.f;
    if (act) {
      if (VEC == 4) { float4 a = *(const float4*)p0; h0[0] = a.x; h0[1] = a.y; h0[2] = a.z; h0[3] = a.w; }
      else          { float2 a = *(const float2*)p0; h0[0] = a.x; h0[1] = a.y; }
    }
    float d0 = 0.f;
#pragma unroll
    for (int j = 0; j < VEC; j++) d0 = fmaf(hd[j], h0[j], d0);
    d0 = wave_sum(d0);
    float w0 = __expf(bd * d0 * r0);
    s += w0;
#pragma unroll
    for (int j = 0; j < VEC; j++) acc[j] = fmaf(w0, h0[j], acc[j]);
  }

  float rs = 1.0f / fmaxf(s, EPSN);
  float o[VEC];
#pragma unroll
  for (int j = 0; j < VEC; j++) {
    float val = acc[j] * rs;
    val = (val <= 0.0f) ? 0.0f : val;            // ReLU; NaN propagates
    if (DROP) val = dropf(val, k0, k1, (unsigned)(v * D + lane * VEC + j));
    o[j] = act ? val : 0.0f;
  }
  if (G3FUSE) {
    // lane holds cols 2*lane, 2*lane+1 (VEC==2); W3[k][j] = W3g[2k+j]
    float p0 = 0.f, p1 = 0.f;
    if (act) {
      float w00 = W3g[4 * lane], w01 = W3g[4 * lane + 1];
      float w10 = W3g[4 * lane + 2], w11 = W3g[4 * lane + 3];
      p0 = o[0] * w00 + o[1] * w10;
      p1 = o[0] * w01 + o[1] * w11;
    }
    p0 = wave_sum(p0); p1 = wave_sum(p1);
    if (lane == 0) {
      H3[2 * v] = p0; H3[2 * v + 1] = p1;
      RINVO[v] = 1.0f / fmaxf(sqrtf(p0 * p0 + p1 * p1), EPSN);   // RINVO != RINV (R8 race)
    }
  } else if (act) {
    float* orow = OUT + (size_t)v * D + lane * VEC;
    if (VEC == 4) *(float4*)orow = make_float4(o[0], o[1], o[2], o[3]);
    else          *(float2*)orow = make_float2(o[0], o[1]);
  }
}

__global__ __launch_bounds__(256) void attn1_kernel(const float* H, const float* RINV,
                                                    const int* OFFS, const int* ESRC,
                                                    const float* BETA, float* OUT,
                                                    unsigned k0, unsigned k1) {
  attn_body<200, 4, true, false>(H, RINV, OFFS, ESRC, BETA, OUT, nullptr, nullptr, nullptr, k0, k1);
}
__global__ __launch_bounds__(256) void attn2g3_kernel(const float* H, const float* RINV,
                                                      const int* OFFS, const int* ESRC,
                                                      const float* BETA, const float* W3g,
                                                      float* H3, float* RINV3,
                                                      unsigned k0, unsigned k1) {
  attn_body<100, 2, true, true>(H, RINV, OFFS, ESRC, BETA, nullptr, W3g, H3, RINV3, k0, k1);
}

// ---------------- layer-3 attention: lanes over edges, f32 output ----------------
__global__ __launch_bounds__(256) void attn3_kernel(const float* __restrict__ H3,
                                                    const float* __restrict__ RINV3,
                                                    const int* __restrict__ OFFS,
                                                    const int* __restrict__ ESRC,
                                                    const float* __restrict__ BETA,
                                                    float* __restrict__ out) {
  int v = blockIdx.x * 4 + (threadIdx.x >> 6);
  int lane = threadIdx.x & 63;
  float bd = BETA[0] * RINV3[v];
  float h0 = H3[2 * v], h1 = H3[2 * v + 1];
  int e0 = OFFS[v], e1 = OFFS[v + 1];
  float s = 0.f, a0 = 0.f, a1 = 0.f;
  for (int idx = e0 + lane; idx < e1; idx += 64) {
    int u = ESRC[idx];
    float s0 = H3[2 * u], s1 = H3[2 * u + 1];
    float w = __expf(bd * (h0 * s0 + h1 * s1) * RINV3[u]);
    s += w; a0 = fmaf(w, s0, a0); a1 = fmaf(w, s1, a1);
  }
  s = wave_sum(s); a0 = wave_sum(a0); a1 = wave_sum(a1);
  if (lane == 0) {
    float rs = 1.0f / fmaxf(s, EPSN);
    float o0 = a0 * rs, o1 = a1 * rs;
    out[2 * v]     = (o0 <= 0.0f) ? 0.0f : o0;
    out[2 * v + 1] = (o1 <= 0.0f) ? 0.0f : o1;
  }
}

// ---------------- host ----------------
extern "C" void kernel_launch(void* const* d_in, const int* in_sizes, int n_in,
                              void* d_out, int out_size, void* d_ws, size_t ws_size,
                              hipStream_t stream) {
  const float* X  = (const float*)d_in[0];
  const int*   EI = (const int*)d_in[1];
  const float* W1 = (const float*)d_in[2];
  const float* W2 = (const float*)d_in[3];
  const float* W3 = (const float*)d_in[4];
  const float* B1 = (const float*)d_in[5];
  const float* B2 = (const float*)d_in[6];
  const float* B3 = (const float*)d_in[7];

  char* ws = (char*)d_ws;
  float* H     = (float*)(ws + H_OFF);
  float* A     = (float*)(ws + A_OFF);
  float* H3    = (float*)(ws + H3_OFF);
  float* RINV  = (float*)(ws + RINV_OFF);
  float* RINV3 = (float*)(ws + RINV3_OFF);
  int* OFFS    = (int*)(ws + OFFS_OFF);
  int* DEG     = (int*)(ws + DEG_OFF);
  int* CURS    = (int*)(ws + CURS_OFF);
  int* ESRC    = (int*)(ws + ESRC_OFF);
  int* CHNK    = (int*)(ws + CHNK_OFF);

  unsigned k1a = 0u, k1b = 0u; tf20(0u, 42u, k1a, k1b);
  unsigned k2a = 0u, k2b = 1u; tf20(0u, 42u, k2a, k2b);

  // CSR by dst
  csr_zero_kernel<<<64, 256, 0, stream>>>(DEG, NN);
  csr_hist_kernel<<<(TE + 255) / 256, 256, 0, stream>>>(EI, DEG);
  csr_scan1_kernel<<<49, 256, 0, stream>>>(DEG, OFFS, CHNK);
  csr_scan2_kernel<<<1, 64, 0, stream>>>(CHNK);
  csr_scan3_kernel<<<196, 256, 0, stream>>>(OFFS, CHNK, CURS);
  csr_scatter_kernel<<<(TE + 255) / 256, 256, 0, stream>>>(EI, CURS, ESRC);

  const int gb = (NN + 63) / 64;     // 782 blocks (~3.05/CU, balanced)
  const int ab = NN / 4;             // 12500

  // layer 1: 128 -> 200
  gemm1_kernel<<<gb, 256, 0, stream>>>(X, W1, H, RINV, NN);
  attn1_kernel<<<ab, 256, 0, stream>>>(H, RINV, OFFS, ESRC, B1, A, k1a, k1b);
  // layer 2: 200 -> 100, layer-3 projection fused into attention epilogue
  gemm2_kernel<<<gb, 256, 0, stream>>>(A, W2, H, RINV, NN);
  attn2g3_kernel<<<ab, 256, 0, stream>>>(H, RINV, OFFS, ESRC, B2, W3, H3, RINV3, k2a, k2b);
  // layer 3 attention
  attn3_kernel<<<ab, 256, 0, stream>>>(H3, RINV3, OFFS, ESRC, B3, (float*)d_out);
}

// Round 10
// 557.758 us; speedup vs baseline: 1.0697x; 1.0697x over previous
//
#include <hip/hip_runtime.h>
#include <hip/hip_bf16.h>

#define NN 50000
#define NE 800000
#define TE 850000
#define EPSN 1e-12f

// Validated: inputs/outputs f32 (R2/R4); partitionable threefry (R2/R4); exp w/o max OK;
// bf16 intermediates FAIL (R5); hier scan (R6); RINV3 must be distinct from RINV (R8 race);
// GEMM needs BOTH balanced grid (R9: 782 blocks) AND >=2 rows/thread register blocking
// (R7 vs R9: 1 row/thread doubles LDS bytes/FMA -> LDS-bound, 145us).

// ---- workspace layout (bytes, 16B aligned) ----
#define H_OFF    0ull          // f32 [50000][200] : H1 then H2
#define A_OFF    40000000ull   // f32 [50000][200] : A1
#define H3_OFF   80000000ull   // f32 [50000][2]
#define RINV_OFF 80400000ull   // f32 [50000]   (layer-1 then layer-2 norms)
#define OFFS_OFF 80600000ull   // int [50001]
#define DEG_OFF  80800016ull   // int [50000]
#define CURS_OFF 81000016ull   // int [50000]
#define ESRC_OFF 81200016ull   // int [850000]
#define CHNK_OFF 84600016ull   // int [64]
#define RINV3_OFF 84600272ull  // f32 [50000]   (layer-3 norms)

// ---------------- threefry2x32, 20 rounds ----------------
__host__ __device__ inline void tf20(unsigned k0, unsigned k1, unsigned& x0, unsigned& x1) {
  unsigned ks2 = k0 ^ k1 ^ 0x1BD11BDAu;
  x0 += k0; x1 += k1;
#define TFR(r) { x0 += x1; x1 = ((x1 << (r)) | (x1 >> (32 - (r)))) ^ x0; }
  TFR(13) TFR(15) TFR(26) TFR(6)
  x0 += k1;  x1 += ks2 + 1u;
  TFR(17) TFR(29) TFR(16) TFR(24)
  x0 += ks2; x1 += k0 + 2u;
  TFR(13) TFR(15) TFR(26) TFR(6)
  x0 += k0;  x1 += k1 + 3u;
  TFR(17) TFR(29) TFR(16) TFR(24)
  x0 += k1;  x1 += ks2 + 4u;
  TFR(13) TFR(15) TFR(26) TFR(6)
  x0 += ks2; x1 += k0 + 5u;
#undef TFR
}

__device__ __forceinline__ float dropf(float val, unsigned k0, unsigned k1, unsigned i) {
  unsigned x0 = 0u, x1 = i;
  tf20(k0, k1, x0, x1);
  unsigned bits = x0 ^ x1;
  float u = __uint_as_float((bits >> 9) | 0x3F800000u) - 1.0f;
  return (u < 0.9f) ? val * (1.0f / 0.9f) : 0.0f;
}

__device__ __forceinline__ float wave_sum(float x) {
  x += __shfl_xor(x, 32); x += __shfl_xor(x, 16); x += __shfl_xor(x, 8);
  x += __shfl_xor(x, 4);  x += __shfl_xor(x, 2);  x += __shfl_xor(x, 1);
  return x;
}

// ---------------- CSR build (R7-validated) ----------------
__global__ __launch_bounds__(256) void csr_zero_kernel(int* __restrict__ p, int n) {
  int stride = gridDim.x * 256;
  for (int i = blockIdx.x * 256 + threadIdx.x; i < n; i += stride) p[i] = 0;
}

__global__ __launch_bounds__(256) void csr_hist_kernel(const int* __restrict__ ei, int* __restrict__ deg) {
  int e = blockIdx.x * 256 + threadIdx.x;
  if (e >= TE) return;
  int d = (e < NE) ? ei[NE + e] : (e - NE);
  atomicAdd(&deg[d], 1);
}

__global__ __launch_bounds__(256) void csr_scan1_kernel(const int* __restrict__ deg,
                                                        int* __restrict__ offs,
                                                        int* __restrict__ chunk) {
  __shared__ int lds[8];
  int t = threadIdx.x;
  int base = blockIdx.x * 1024 + t * 4;
  int d[4];
#pragma unroll
  for (int j = 0; j < 4; j++) d[j] = (base + j < NN) ? deg[base + j] : 0;
  int ts = d[0] + d[1] + d[2] + d[3];
  int lane = t & 63, wave = t >> 6;
  int inc = ts;
#pragma unroll
  for (int sh = 1; sh < 64; sh <<= 1) { int u = __shfl_up(inc, sh); if (lane >= sh) inc += u; }
  if (lane == 63) lds[wave] = inc;
  __syncthreads();
  if (t == 0) { int s = 0; for (int w = 0; w < 4; w++) { int x = lds[w]; lds[w] = s; s += x; } lds[4] = s; }
  __syncthreads();
  int p = lds[wave] + inc - ts;
#pragma unroll
  for (int j = 0; j < 4; j++) { if (base + j < NN) offs[base + j] = p; p += d[j]; }
  if (t == 255) chunk[blockIdx.x] = lds[4];
}

__global__ __launch_bounds__(64) void csr_scan2_kernel(int* __restrict__ chunk) {
  int t = threadIdx.x;
  int v = (t < 49) ? chunk[t] : 0;
  int inc = v;
#pragma unroll
  for (int sh = 1; sh < 64; sh <<= 1) { int u = __shfl_up(inc, sh); if (t >= sh) inc += u; }
  if (t < 49) chunk[t] = inc - v;
}

__global__ __launch_bounds__(256) void csr_scan3_kernel(int* __restrict__ offs,
                                                        const int* __restrict__ chunk,
                                                        int* __restrict__ curs) {
  int i = blockIdx.x * 256 + threadIdx.x;
  if (i < NN) {
    int val = offs[i] + chunk[i >> 10];
    offs[i] = val;
    curs[i] = val;
  }
  if (i == 0) offs[NN] = TE;
}

__global__ __launch_bounds__(256) void csr_scatter_kernel(const int* __restrict__ ei,
                                                          int* __restrict__ curs,
                                                          int* __restrict__ esrc) {
  int e = blockIdx.x * 256 + threadIdx.x;
  if (e >= TE) return;
  int s, d;
  if (e < NE) { s = ei[e]; d = ei[NE + e]; } else { s = d = e - NE; }
  int pos = atomicAdd(&curs[d], 1);
  esrc[pos] = s;
}

// ---------------- tiled f32 GEMM: 64-row tiles (782 blocks) x 2 rows/thread ----------------
// thread (rgrp=t>>3 in 0..31 -> rows rgrp*2,rgrp*2+1; cg=t&7 -> CPT=NLP/8 cols).
// LDS ~2.1 B/FMA (R7 ratio) on the balanced grid (R9 ratio fix).
template<int K, int KT, int NLP, int N>
__device__ __forceinline__ void gemm_body(const float* __restrict__ A,
                                          const float* __restrict__ W,
                                          float* __restrict__ H,
                                          float* __restrict__ RINV, int M) {
  constexpr int CPT = NLP / 8, KTP = KT + 1, NV = N / 4, QV = CPT / 4;
  __shared__ float As[64 * KTP];
  __shared__ float Ws[KT * NLP];
  const float4* A4 = (const float4*)A;
  const float4* W4 = (const float4*)W;
  const float4* Ws4 = (const float4*)Ws;

  int t = threadIdx.x, rgrp = t >> 3, cg = t & 7;
  int row0 = blockIdx.x * 64;
  float acc0[CPT], acc1[CPT];
#pragma unroll
  for (int j = 0; j < CPT; j++) { acc0[j] = 0.f; acc1[j] = 0.f; }

  for (int k0 = 0; k0 < K; k0 += KT) {
    __syncthreads();
    for (int idx = t; idx < 64 * (KT / 4); idx += 256) {
      int r = idx / (KT / 4), cq = idx - r * (KT / 4);
      int gr = row0 + r;
      float4 v = (gr < M) ? A4[(size_t)gr * (K / 4) + (k0 / 4) + cq]
                          : make_float4(0.f, 0.f, 0.f, 0.f);
      float* dst = &As[r * KTP + cq * 4];
      dst[0] = v.x; dst[1] = v.y; dst[2] = v.z; dst[3] = v.w;
    }
    for (int idx = t; idx < KT * NV; idx += 256) {
      int kk = idx / NV, cq = idx - kk * NV;
      *(float4*)&Ws[kk * NLP + cq * 4] = W4[(size_t)(k0 + kk) * NV + cq];
    }
    if (NLP > N) {
      for (int idx = t; idx < KT * ((NLP - N) / 4); idx += 256) {
        int kk = idx / ((NLP - N) / 4), cq = idx - kk * ((NLP - N) / 4);
        *(float4*)&Ws[kk * NLP + N + cq * 4] = make_float4(0.f, 0.f, 0.f, 0.f);
      }
    }
    __syncthreads();
#pragma unroll
    for (int kk = 0; kk < KT; kk++) {
      float a0 = As[(rgrp * 2) * KTP + kk];
      float a1 = As[(rgrp * 2 + 1) * KTP + kk];
#pragma unroll
      for (int q = 0; q < QV; q++) {
        float4 wv = Ws4[(kk * NLP + cg * CPT) / 4 + q];
        acc0[q * 4 + 0] = fmaf(a0, wv.x, acc0[q * 4 + 0]);
        acc0[q * 4 + 1] = fmaf(a0, wv.y, acc0[q * 4 + 1]);
        acc0[q * 4 + 2] = fmaf(a0, wv.z, acc0[q * 4 + 2]);
        acc0[q * 4 + 3] = fmaf(a0, wv.w, acc0[q * 4 + 3]);
        acc1[q * 4 + 0] = fmaf(a1, wv.x, acc1[q * 4 + 0]);
        acc1[q * 4 + 1] = fmaf(a1, wv.y, acc1[q * 4 + 1]);
        acc1[q * 4 + 2] = fmaf(a1, wv.z, acc1[q * 4 + 2]);
        acc1[q * 4 + 3] = fmaf(a1, wv.w, acc1[q * 4 + 3]);
      }
    }
  }

  int r0 = row0 + rgrp * 2;
#pragma unroll
  for (int rr = 0; rr < 2; rr++) {
    int gr = r0 + rr;
    const float* acc = rr ? acc1 : acc0;
    float ss = 0.f;
#pragma unroll
    for (int j = 0; j < CPT; j++) {
      float v = acc[j];
      ss += v * v;                               // pad cols exactly 0
      int c = cg * CPT + j;
      if (gr < M && c < N) H[(size_t)gr * N + c] = v;
    }
    // sum across the 8 col-groups of this row (lanes differ in bits 0..2)
    ss += __shfl_xor(ss, 1); ss += __shfl_xor(ss, 2); ss += __shfl_xor(ss, 4);
    if (cg == 0 && gr < M) RINV[gr] = 1.0f / fmaxf(sqrtf(ss), EPSN);
  }
}

__global__ __launch_bounds__(256) void gemm1_kernel(const float* A, const float* W,
                                                    float* H, float* RINV, int M) {
  gemm_body<128, 32, 224, 200>(A, W, H, RINV, M);   // CPT=28, LDS 37.1 KB
}
__global__ __launch_bounds__(256) void gemm2_kernel(const float* A, const float* W,
                                                    float* H, float* RINV, int M) {
  gemm_body<200, 40, 128, 100>(A, W, H, RINV, M);   // CPT=16, LDS 30.7 KB
}

// ---------------- fused attention: wave/dst, vectorized gathers, 4-edge unroll ----------------
template<int D, int VEC, bool DROP, bool G3FUSE>
__device__ __forceinline__ void attn_body(const float* __restrict__ H,
                                          const float* __restrict__ RINV,
                                          const int* __restrict__ OFFS,
                                          const int* __restrict__ ESRC,
                                          const float* __restrict__ BETA,
                                          float* __restrict__ OUT,
                                          const float* __restrict__ W3g,
                                          float* __restrict__ H3,
                                          float* __restrict__ RINVO,
                                          unsigned k0, unsigned k1) {
  constexpr int NL = D / VEC;                  // 50 active lanes
  int v = blockIdx.x * 4 + (threadIdx.x >> 6);
  int lane = threadIdx.x & 63;
  bool act = lane < NL;
  const float* hrow = H + (size_t)v * D + lane * VEC;
  float hd[VEC];
#pragma unroll
  for (int j = 0; j < VEC; j++) hd[j] = 0.f;
  if (act) {
    if (VEC == 4) { float4 tv = *(const float4*)hrow; hd[0] = tv.x; hd[1] = tv.y; hd[2] = tv.z; hd[3] = tv.w; }
    else          { float2 tv = *(const float2*)hrow; hd[0] = tv.x; hd[1] = tv.y; }
  }
  float bd = BETA[0] * RINV[v];
  int e0 = OFFS[v], e1 = OFFS[v + 1];

  float s = 0.0f;
  float acc[VEC];
#pragma unroll
  for (int j = 0; j < VEC; j++) acc[j] = 0.0f;

  int idx = e0;
  for (; idx + 4 <= e1; idx += 4) {
    int   u[4];
    float r[4], dt[4], hs[4][VEC];
#pragma unroll
    for (int m = 0; m < 4; m++) u[m] = ESRC[idx + m];
#pragma unroll
    for (int m = 0; m < 4; m++) r[m] = RINV[u[m]];
#pragma unroll
    for (int m = 0; m < 4; m++) {
      const float* p = H + (size_t)u[m] * D + lane * VEC;
#pragma unroll
      for (int j = 0; j < VEC; j++) hs[m][j] = 0.f;
      if (act) {
        if (VEC == 4) { float4 a = *(const float4*)p; hs[m][0] = a.x; hs[m][1] = a.y; hs[m][2] = a.z; hs[m][3] = a.w; }
        else          { float2 a = *(const float2*)p; hs[m][0] = a.x; hs[m][1] = a.y; }
      }
    }
#pragma unroll
    for (int m = 0; m < 4; m++) {
      float d = 0.f;
#pragma unroll
      for (int j = 0; j < VEC; j++) d = fmaf(hd[j], hs[m][j], d);
      dt[m] = wave_sum(d);
    }
#pragma unroll
    for (int m = 0; m < 4; m++) {
      float w = __expf(bd * dt[m] * r[m]);
      s += w;
#pragma unroll
      for (int j = 0; j < VEC; j++) acc[j] = fmaf(w, hs[m][j], acc[j]);
    }
  }
  for (; idx < e1; ++idx) {
    int u0 = ESRC[idx];
    float r0 = RINV[u0];
    const float* p0 = H + (size_t)u0 * D + lane * VEC;
    float h0[VEC];
#pragma unroll
    for (int j = 0; j < VEC; j++) h0[j] = 0.f;
    if (act) {
      if (VEC == 4) { float4 a = *(const float4*)p0; h0[0] = a.x; h0[1] = a.y; h0[2] = a.z; h0[3] = a.w; }
      else          { float2 a = *(const float2*)p0; h0[0] = a.x; h0[1] = a.y; }
    }
    float d0 = 0.f;
#pragma unroll
    for (int j = 0; j < VEC; j++) d0 = fmaf(hd[j], h0[j], d0);
    d0 = wave_sum(d0);
    float w0 = __expf(bd * d0 * r0);
    s += w0;
#pragma unroll
    for (int j = 0; j < VEC; j++) acc[j] = fmaf(w0, h0[j], acc[j]);
  }

  float rs = 1.0f / fmaxf(s, EPSN);
  float o[VEC];
#pragma unroll
  for (int j = 0; j < VEC; j++) {
    float val = acc[j] * rs;
    val = (val <= 0.0f) ? 0.0f : val;            // ReLU; NaN propagates
    if (DROP) val = dropf(val, k0, k1, (unsigned)(v * D + lane * VEC + j));
    o[j] = act ? val : 0.0f;
  }
  if (G3FUSE) {
    float p0 = 0.f, p1 = 0.f;
    if (act) {
      float w00 = W3g[4 * lane], w01 = W3g[4 * lane + 1];
      float w10 = W3g[4 * lane + 2], w11 = W3g[4 * lane + 3];
      p0 = o[0] * w00 + o[1] * w10;
      p1 = o[0] * w01 + o[1] * w11;
    }
    p0 = wave_sum(p0); p1 = wave_sum(p1);
    if (lane == 0) {
      H3[2 * v] = p0; H3[2 * v + 1] = p1;
      RINVO[v] = 1.0f / fmaxf(sqrtf(p0 * p0 + p1 * p1), EPSN);   // RINVO != RINV (R8 race)
    }
  } else if (act) {
    float* orow = OUT + (size_t)v * D + lane * VEC;
    if (VEC == 4) *(float4*)orow = make_float4(o[0], o[1], o[2], o[3]);
    else          *(float2*)orow = make_float2(o[0], o[1]);
  }
}

__global__ __launch_bounds__(256) void attn1_kernel(const float* H, const float* RINV,
                                                    const int* OFFS, const int* ESRC,
                                                    const float* BETA, float* OUT,
                                                    unsigned k0, unsigned k1) {
  attn_body<200, 4, true, false>(H, RINV, OFFS, ESRC, BETA, OUT, nullptr, nullptr, nullptr, k0, k1);
}
__global__ __launch_bounds__(256) void attn2g3_kernel(const float* H, const float* RINV,
                                                      const int* OFFS, const int* ESRC,
                                                      const float* BETA, const float* W3g,
                                                      float* H3, float* RINV3,
                                                      unsigned k0, unsigned k1) {
  attn_body<100, 2, true, true>(H, RINV, OFFS, ESRC, BETA, nullptr, W3g, H3, RINV3, k0, k1);
}

// ---------------- layer-3 attention: lanes over edges, f32 output ----------------
__global__ __launch_bounds__(256) void attn3_kernel(const float* __restrict__ H3,
                                                    const float* __restrict__ RINV3,
                                                    const int* __restrict__ OFFS,
                                                    const int* __restrict__ ESRC,
                                                    const float* __restrict__ BETA,
                                                    float* __restrict__ out) {
  int v = blockIdx.x * 4 + (threadIdx.x >> 6);
  int lane = threadIdx.x & 63;
  float bd = BETA[0] * RINV3[v];
  float h0 = H3[2 * v], h1 = H3[2 * v + 1];
  int e0 = OFFS[v], e1 = OFFS[v + 1];
  float s = 0.f, a0 = 0.f, a1 = 0.f;
  for (int idx = e0 + lane; idx < e1; idx += 64) {
    int u = ESRC[idx];
    float s0 = H3[2 * u], s1 = H3[2 * u + 1];
    float w = __expf(bd * (h0 * s0 + h1 * s1) * RINV3[u]);
    s += w; a0 = fmaf(w, s0, a0); a1 = fmaf(w, s1, a1);
  }
  s = wave_sum(s); a0 = wave_sum(a0); a1 = wave_sum(a1);
  if (lane == 0) {
    float rs = 1.0f / fmaxf(s, EPSN);
    float o0 = a0 * rs, o1 = a1 * rs;
    out[2 * v]     = (o0 <= 0.0f) ? 0.0f : o0;
    out[2 * v + 1] = (o1 <= 0.0f) ? 0.0f : o1;
  }
}

// ---------------- host ----------------
extern "C" void kernel_launch(void* const* d_in, const int* in_sizes, int n_in,
                              void* d_out, int out_size, void* d_ws, size_t ws_size,
                              hipStream_t stream) {
  const float* X  = (const float*)d_in[0];
  const int*   EI = (const int*)d_in[1];
  const float* W1 = (const float*)d_in[2];
  const float* W2 = (const float*)d_in[3];
  const float* W3 = (const float*)d_in[4];
  const float* B1 = (const float*)d_in[5];
  const float* B2 = (const float*)d_in[6];
  const float* B3 = (const float*)d_in[7];

  char* ws = (char*)d_ws;
  float* H     = (float*)(ws + H_OFF);
  float* A     = (float*)(ws + A_OFF);
  float* H3    = (float*)(ws + H3_OFF);
  float* RINV  = (float*)(ws + RINV_OFF);
  float* RINV3 = (float*)(ws + RINV3_OFF);
  int* OFFS    = (int*)(ws + OFFS_OFF);
  int* DEG     = (int*)(ws + DEG_OFF);
  int* CURS    = (int*)(ws + CURS_OFF);
  int* ESRC    = (int*)(ws + ESRC_OFF);
  int* CHNK    = (int*)(ws + CHNK_OFF);

  unsigned k1a = 0u, k1b = 0u; tf20(0u, 42u, k1a, k1b);
  unsigned k2a = 0u, k2b = 1u; tf20(0u, 42u, k2a, k2b);

  // CSR by dst
  csr_zero_kernel<<<64, 256, 0, stream>>>(DEG, NN);
  csr_hist_kernel<<<(TE + 255) / 256, 256, 0, stream>>>(EI, DEG);
  csr_scan1_kernel<<<49, 256, 0, stream>>>(DEG, OFFS, CHNK);
  csr_scan2_kernel<<<1, 64, 0, stream>>>(CHNK);
  csr_scan3_kernel<<<196, 256, 0, stream>>>(OFFS, CHNK, CURS);
  csr_scatter_kernel<<<(TE + 255) / 256, 256, 0, stream>>>(EI, CURS, ESRC);

  const int gb = (NN + 63) / 64;     // 782 blocks (~3.05/CU, balanced)
  const int ab = NN / 4;             // 12500

  // layer 1: 128 -> 200
  gemm1_kernel<<<gb, 256, 0, stream>>>(X, W1, H, RINV, NN);
  attn1_kernel<<<ab, 256, 0, stream>>>(H, RINV, OFFS, ESRC, B1, A, k1a, k1b);
  // layer 2: 200 -> 100, layer-3 projection fused into attention epilogue
  gemm2_kernel<<<gb, 256, 0, stream>>>(A, W2, H, RINV, NN);
  attn2g3_kernel<<<ab, 256, 0, stream>>>(H, RINV, OFFS, ESRC, B2, W3, H3, RINV3, k2a, k2b);
  // layer 3 attention
  attn3_kernel<<<ab, 256, 0, stream>>>(H3, RINV3, OFFS, ESRC, B3, (float*)d_out);
}